// Round 1
// baseline (1578.097 us; speedup 1.0000x reference)
//
#include <hip/hip_runtime.h>

// MultiHeadAttention — MI355X (gfx950)
// B=8, N=4096, DIM=2048, H=16, hd=128.
// Pipeline: cast->bf16, QKV GEMM (256^2 8-phase MFMA), per-token head-attention
// (+permute), proj GEMM (256^2 8-phase).
//
// GEMM = learn_hip m201/m204 template: BM=BN=256, BK=64, 8 waves (2Mx4N),
// 128 KiB LDS double-buffer, st_16x32 XOR swizzle (pre-swizzled global src,
// swizzled ds_read), counted vmcnt(6), setprio around MFMA, XCD block swizzle.

typedef unsigned short u16;
typedef unsigned int   u32;
typedef __bf16  bf16x8  __attribute__((ext_vector_type(8)));
typedef float   floatx4 __attribute__((ext_vector_type(4)));

#define GAS __attribute__((address_space(1)))
#define LAS __attribute__((address_space(3)))

__device__ __forceinline__ u16 f2bf(float x) {
  u32 u = __builtin_bit_cast(u32, x);
  return (u16)((u + 0x7FFFu + ((u >> 16) & 1u)) >> 16);
}
__device__ __forceinline__ u32 f2bf2(float lo, float hi) {
  u32 a = __builtin_bit_cast(u32, lo);
  u32 b = __builtin_bit_cast(u32, hi);
  a = (a + 0x7FFFu + ((a >> 16) & 1u)) >> 16;
  b = (b + 0x7FFFu + ((b >> 16) & 1u)) >> 16;
  return a | (b << 16);
}
__device__ __forceinline__ float bf2f(u32 lo16) {
  return __builtin_bit_cast(float, lo16 << 16);
}
__device__ __forceinline__ void unpack8(uint4 r, float* f) {
  f[0] = bf2f(r.x & 0xffffu); f[1] = bf2f(r.x >> 16);
  f[2] = bf2f(r.y & 0xffffu); f[3] = bf2f(r.y >> 16);
  f[4] = bf2f(r.z & 0xffffu); f[5] = bf2f(r.z >> 16);
  f[6] = bf2f(r.w & 0xffffu); f[7] = bf2f(r.w >> 16);
}

// ---------------- cast fp32 -> bf16, 8 elems/thread ----------------
__global__ __launch_bounds__(256)
void cast_bf16_k(const float4* __restrict__ in, uint4* __restrict__ out, long n8) {
  long i = (long)blockIdx.x * 256 + threadIdx.x;
  if (i >= n8) return;
  float4 a = in[2 * i], b = in[2 * i + 1];
  uint4 o;
  o.x = f2bf2(a.x, a.y); o.y = f2bf2(a.z, a.w);
  o.z = f2bf2(b.x, b.y); o.w = f2bf2(b.z, b.w);
  out[i] = o;
}

// ---------------- C = A(MxK) @ B(NxK)^T — 256^2 8-phase template ----------------
// LDS layout per tile (256x64 bf16 = 32 KiB): subtiled [rowblk16][colblk32][16][32],
// st_16x32 swizzle: inner byte ^= ((inner>>9)&1)<<5  (col-bit4 ^= row-bit3).
// global_load_lds writes LDS linearly -> global source is inverse-swizzled per lane.
__device__ __forceinline__ void mfma_quad(floatx4 (&acc)[8][4], const bf16x8 (&af)[2][4],
                                          const bf16x8 (&bv)[2][4], int ib, int nb) {
#pragma unroll
  for (int kk = 0; kk < 2; ++kk)
#pragma unroll
    for (int i = 0; i < 4; ++i)
#pragma unroll
      for (int n = 0; n < 2; ++n)
        acc[ib + i][nb + n] = __builtin_amdgcn_mfma_f32_16x16x32_bf16(
            af[kk][i], bv[kk][nb + n], acc[ib + i][nb + n], 0, 0, 0);
}

template<int OUT_BF16>
__global__ __launch_bounds__(512, 2)
void gemm256_k(const u16* __restrict__ A, const u16* __restrict__ B,
               void* __restrict__ Cv, int N_, int K, int nbx)
{
  // buf b: A-tile at b*65536, B-tile at b*65536+32768
  __shared__ __align__(16) char smem[131072];

  // bijective XCD swizzle (grid % 8 == 0 by construction)
  const int nwg = (int)gridDim.x;
  const int id  = (int)blockIdx.x;
  const int swz = (id & 7) * (nwg >> 3) + (id >> 3);
  const int bx = swz % nbx, by = swz / nbx;
  const long tileM = (long)by << 8, tileN = (long)bx << 8;

  const int t = (int)threadIdx.x;
  const int wave = t >> 6, lane = t & 63;
  const int wm = wave >> 2, wn = wave & 3;      // 2 x 4 wave grid
  const int lrow = lane & 15, lkq = lane >> 4;

  // ---- staging: per-thread inverse-swizzled global source (16 B / lane / issue)
  // LDS linear offset o = issue*8192 + t*16 within a tile; invert layout+swizzle:
  const int o0   = t << 4;
  const int r0   = (o0 >> 6) & 15;
  const int c0   = (o0 & 63) ^ ((r0 & 8) << 2);          // inverse st_16x32 (involution)
  const int row0 = ((o0 >> 11) << 4) | r0;               // 0..63 (issue adds 64 rows)
  const int col0 = (((o0 >> 10) & 1) << 5) + (c0 >> 1);  // u16 col within K-step

  const u16* pA = A + (tileM + row0) * (long)K + col0;
  const u16* pB = B + (tileN + row0) * (long)K + col0;
  const long rs64 = (long)K << 6;   // 64 rows worth of u16 elements
  const int  nkt  = K >> 6;         // number of 64-wide K-tiles

  // ---- fragment ds_read bases (byte offsets, swizzle folded per-lane)
  const int innerF = (lrow << 6) | ((lkq << 4) ^ ((lrow & 8) << 2));
  const int aB = (wm << 14) + innerF;            // + i*2048 + kk*1024
  const int bB = 32768 + (wn << 13) + innerF;    // + n*2048 + kk*1024

  floatx4 acc[8][4] = {};
  bf16x8 af[2][4], bv[2][4];

  // half-tile slots per K-tile, issue order: 0=Bh0 1=Bh1 2=Ah0 3=Ah1 (2 loads each)
  auto stage = [&](int s, int j) {
    const int base = ((j & 1) << 16) + ((s < 2) ? 32768 : 0) + ((s & 1) << 14) + (wave << 10);
    const u16* src = (s < 2) ? pB : pA;
    const long gofs = (long)(s & 1) * 2 * rs64 + ((long)j << 6);
    __builtin_amdgcn_global_load_lds((GAS void*)(src + gofs),        (LAS void*)(smem + base),        16, 0, 0);
    __builtin_amdgcn_global_load_lds((GAS void*)(src + gofs + rs64), (LAS void*)(smem + base + 8192), 16, 0, 0);
  };

  // ---- prologue: K-tile 0 fully + K-tile 1 slots 0..2 (lead-7 stream)
  stage(0, 0); stage(1, 0); stage(2, 0); stage(3, 0);
  if (nkt > 1) { stage(0, 1); stage(1, 1); stage(2, 1); }
  asm volatile("s_waitcnt vmcnt(6)" ::: "memory");
  __builtin_amdgcn_s_barrier();
  __builtin_amdgcn_sched_barrier(0);

  for (int j = 0; j < nkt; ++j) {
    const int bufo = (j & 1) << 16;

    // ---------- phase 0: read ALL B frags + A-quad0; stage h=4j+7
    {
#pragma unroll
      for (int kk = 0; kk < 2; ++kk) {
#pragma unroll
        for (int n = 0; n < 4; ++n)
          bv[kk][n] = *(const bf16x8*)(smem + bufo + bB + (n << 11) + (kk << 10));
#pragma unroll
        for (int i = 0; i < 4; ++i)
          af[kk][i] = *(const bf16x8*)(smem + bufo + aB + (i << 11) + (kk << 10));
      }
      const int h = 4 * j + 7;
      if (h < 4 * nkt) stage(h & 3, h >> 2);
      __builtin_amdgcn_s_barrier();
      asm volatile("s_waitcnt lgkmcnt(0)" ::: "memory");
      __builtin_amdgcn_sched_barrier(0);
      __builtin_amdgcn_s_setprio(1);
      mfma_quad(acc, af, bv, 0, 0);
      __builtin_amdgcn_s_setprio(0);
      __builtin_amdgcn_s_barrier();
      __builtin_amdgcn_sched_barrier(0);
    }
    // ---------- phase 1: no reads; stage h=4j+8 (Bh0 of j+2, current buf — B reads done)
    {
      const int h = 4 * j + 8;
      if (h < 4 * nkt) stage(h & 3, h >> 2);
      __builtin_amdgcn_s_barrier();
      asm volatile("s_waitcnt lgkmcnt(0)" ::: "memory");
      __builtin_amdgcn_sched_barrier(0);
      __builtin_amdgcn_s_setprio(1);
      mfma_quad(acc, af, bv, 0, 2);
      __builtin_amdgcn_s_setprio(0);
      __builtin_amdgcn_s_barrier();
      __builtin_amdgcn_sched_barrier(0);
    }
    // ---------- phase 2: read A-quad1; stage h=4j+9 (Bh1 of j+2)
    {
#pragma unroll
      for (int kk = 0; kk < 2; ++kk)
#pragma unroll
        for (int i = 0; i < 4; ++i)
          af[kk][i] = *(const bf16x8*)(smem + bufo + aB + ((4 + i) << 11) + (kk << 10));
      const int h = 4 * j + 9;
      if (h < 4 * nkt) stage(h & 3, h >> 2);
      __builtin_amdgcn_s_barrier();
      asm volatile("s_waitcnt lgkmcnt(0)" ::: "memory");
      __builtin_amdgcn_sched_barrier(0);
      __builtin_amdgcn_s_setprio(1);
      mfma_quad(acc, af, bv, 4, 0);
      __builtin_amdgcn_s_setprio(0);
      __builtin_amdgcn_s_barrier();
      __builtin_amdgcn_sched_barrier(0);
    }
    // ---------- phase 3: stage h=4j+10 (Ah0 of j+2 — A reads done in ph2); counted vmcnt
    {
      const int h = 4 * j + 10;
      if (h < 4 * nkt) stage(h & 3, h >> 2);
      __builtin_amdgcn_s_barrier();
      asm volatile("s_waitcnt lgkmcnt(0)" ::: "memory");
      __builtin_amdgcn_sched_barrier(0);
      __builtin_amdgcn_s_setprio(1);
      mfma_quad(acc, af, bv, 4, 2);
      __builtin_amdgcn_s_setprio(0);
      // ensure K-tile j+1 fully landed; keep 3 half-tiles (6 loads) in flight
      if (j < nkt - 2)       { asm volatile("s_waitcnt vmcnt(6)" ::: "memory"); }
      else if (j == nkt - 2) { asm volatile("s_waitcnt vmcnt(0)" ::: "memory"); }
      __builtin_amdgcn_s_barrier();
      __builtin_amdgcn_sched_barrier(0);
    }
  }

  // ---- epilogue: C/D layout col = lane&15, row = (lane>>4)*4 + reg
#pragma unroll
  for (int i = 0; i < 8; ++i) {
#pragma unroll
    for (int r = 0; r < 4; ++r) {
      const long row = tileM + wm * 128 + i * 16 + lkq * 4 + r;
#pragma unroll
      for (int n = 0; n < 4; ++n) {
        const long col = tileN + wn * 64 + n * 16 + lrow;
        const float v = acc[i][n][r];
        if (OUT_BF16) ((u16*)Cv)[row * (long)N_ + col] = f2bf(v);
        else          ((float*)Cv)[row * (long)N_ + col] = v;
      }
    }
  }
}

// ---------------- per-token 16-head x 16-head attention + permute ----------------
__global__ __launch_bounds__(256)
void attn_k(const u16* __restrict__ qkv, u16* __restrict__ y)
{
  __shared__ float sq[16 * 132];
  __shared__ float skT[128 * 17];
  __shared__ float sv[16 * 128];
  __shared__ float sS[16 * 17];
  __shared__ float sP[16 * 17];

  const int t = threadIdx.x;
  const int token = blockIdx.x;        // b*4096 + n
  const int n = token & 4095;
  const int b = token >> 12;
  const u16* base = qkv + (long)token * 6144;

  float f[8];
  { // q
    uint4 raw = *(const uint4*)(base + t * 8);
    unpack8(raw, f);
    float* dst = &sq[(t >> 4) * 132 + (t & 15) * 8];
    ((float4*)dst)[0] = make_float4(f[0], f[1], f[2], f[3]);
    ((float4*)dst)[1] = make_float4(f[4], f[5], f[6], f[7]);
  }
  { // k -> transposed
    uint4 raw = *(const uint4*)(base + 2048 + t * 8);
    unpack8(raw, f);
    const int j = t >> 4;
    const int d0 = (t & 15) * 8;
#pragma unroll
    for (int e = 0; e < 8; ++e) skT[(d0 + e) * 17 + j] = f[e];
  }
  { // v
    uint4 raw = *(const uint4*)(base + 4096 + t * 8);
    unpack8(raw, f);
    float* dst = &sv[t * 8];
    ((float4*)dst)[0] = make_float4(f[0], f[1], f[2], f[3]);
    ((float4*)dst)[1] = make_float4(f[4], f[5], f[6], f[7]);
  }
  __syncthreads();

  { // scores
    const int i = t >> 4, j = t & 15;
    const float* qi = &sq[i * 132];
    float s = 0.f;
#pragma unroll 16
    for (int d = 0; d < 128; ++d) s += qi[d] * skT[d * 17 + j];
    sS[i * 17 + j] = s * 0.08838834764831845f;
  }
  __syncthreads();

  { // softmax over j
    const int i = t >> 4, j = t & 15;
    float mx = -1e30f;
#pragma unroll
    for (int jj = 0; jj < 16; ++jj) mx = fmaxf(mx, sS[i * 17 + jj]);
    float sum = 0.f;
#pragma unroll
    for (int jj = 0; jj < 16; ++jj) sum += __expf(sS[i * 17 + jj] - mx);
    sP[i * 17 + j] = __expf(sS[i * 17 + j] - mx) / sum;
  }
  __syncthreads();

  { // out + permute
    const int i = t & 15, dblk = t >> 4;
    float o[8] = {};
#pragma unroll
    for (int jj = 0; jj < 16; ++jj) {
      const float p = sP[i * 17 + jj];
      const float* vv = &sv[jj * 128 + dblk * 8];
#pragma unroll
      for (int e = 0; e < 8; ++e) o[e] += p * vv[e];
    }
    const long row  = (long)b * 4096 + i * 256 + (n >> 4);
    const long colb = (long)(n & 15) * 128 + dblk * 8;
    uint4 pk;
    pk.x = f2bf2(o[0], o[1]); pk.y = f2bf2(o[2], o[3]);
    pk.z = f2bf2(o[4], o[5]); pk.w = f2bf2(o[6], o[7]);
    *(uint4*)&y[row * 2048 + colb] = pk;
  }
}

// ---------------- launch ----------------
extern "C" void kernel_launch(void* const* d_in, const int* in_sizes, int n_in,
                              void* d_out, int out_size, void* d_ws, size_t ws_size,
                              hipStream_t stream)
{
  const float* x      = (const float*)d_in[0];
  const float* w_qkv  = (const float*)d_in[1];
  const float* w_proj = (const float*)d_in[2];

  const long NX  = 67108864L;   // 8*4096*2048
  const long NWQ = 12582912L;   // 6144*2048
  const long NWP = 4194304L;    // 2048*2048
  const long NQKV = 32768L * 6144;
  const long NY   = 32768L * 2048;

  char* ws = (char*)d_ws;
  u16* xb   = (u16*)ws;  ws += NX * 2;
  u16* wqb  = (u16*)ws;  ws += NWQ * 2;
  u16* wpb  = (u16*)ws;  ws += NWP * 2;
  u16* qkvb = (u16*)ws;  ws += NQKV * 2;
  u16* yb   = (u16*)ws;  ws += NY * 2;
  if (ws_size < (size_t)704643072L) return;  // diagnostic: absmax stays ~454

  cast_bf16_k<<<dim3((u32)(NX  / 2048)), 256, 0, stream>>>((const float4*)x,      (uint4*)xb,  NX  / 8);
  cast_bf16_k<<<dim3((u32)(NWQ / 2048)), 256, 0, stream>>>((const float4*)w_qkv,  (uint4*)wqb, NWQ / 8);
  cast_bf16_k<<<dim3((u32)(NWP / 2048)), 256, 0, stream>>>((const float4*)w_proj, (uint4*)wpb, NWP / 8);

  // qkv = x @ w_qkv^T : M=32768, N=6144, K=2048 -> grid 24x128 = 3072 (%8==0)
  gemm256_k<1><<<dim3(24 * 128), 512, 0, stream>>>(xb, wqb, (void*)qkvb, 6144, 2048, 24);

  // head-attention + permute
  attn_k<<<dim3(32768), 256, 0, stream>>>(qkvb, yb);

  // out = y @ w_proj^T : M=32768, N=2048, K=2048 -> grid 8x128 = 1024 (%8==0)
  gemm256_k<0><<<dim3(8 * 128), 512, 0, stream>>>(yb, wpb, d_out, 2048, 2048, 8);
}

// Round 2
// 1542.006 us; speedup vs baseline: 1.0234x; 1.0234x over previous
//
#include <hip/hip_runtime.h>

// MultiHeadAttention — MI355X (gfx950)
// B=8, N=4096, DIM=2048, H=16, hd=128.
// Pipeline: cast->bf16, QKV GEMM (256^2 8-phase MFMA), per-token head-attention
// (+permute), proj GEMM (256^2 8-phase).
//
// GEMM = learn_hip m201/m204 template: BM=BN=256, BK=64, 8 waves (2Mx4N),
// 128 KiB LDS double-buffer, st_16x32 XOR swizzle (pre-swizzled global src,
// swizzled ds_read), counted vmcnt, setprio around MFMA, XCD block swizzle.
// R1 change: kk-split phases -> ds_reads balanced 8/8/4/4 per phase (was 16/0/8/0);
// stages moved to ph0 (A of j+1) and ph2 (B of j+2), vmcnt(4).

typedef unsigned short u16;
typedef unsigned int   u32;
typedef __bf16  bf16x8  __attribute__((ext_vector_type(8)));
typedef float   floatx4 __attribute__((ext_vector_type(4)));

#define GAS __attribute__((address_space(1)))
#define LAS __attribute__((address_space(3)))

__device__ __forceinline__ u16 f2bf(float x) {
  u32 u = __builtin_bit_cast(u32, x);
  return (u16)((u + 0x7FFFu + ((u >> 16) & 1u)) >> 16);
}
__device__ __forceinline__ u32 f2bf2(float lo, float hi) {
  u32 a = __builtin_bit_cast(u32, lo);
  u32 b = __builtin_bit_cast(u32, hi);
  a = (a + 0x7FFFu + ((a >> 16) & 1u)) >> 16;
  b = (b + 0x7FFFu + ((b >> 16) & 1u)) >> 16;
  return a | (b << 16);
}
__device__ __forceinline__ float bf2f(u32 lo16) {
  return __builtin_bit_cast(float, lo16 << 16);
}
__device__ __forceinline__ void unpack8(uint4 r, float* f) {
  f[0] = bf2f(r.x & 0xffffu); f[1] = bf2f(r.x >> 16);
  f[2] = bf2f(r.y & 0xffffu); f[3] = bf2f(r.y >> 16);
  f[4] = bf2f(r.z & 0xffffu); f[5] = bf2f(r.z >> 16);
  f[6] = bf2f(r.w & 0xffffu); f[7] = bf2f(r.w >> 16);
}

// ---------------- cast fp32 -> bf16, 8 elems/thread ----------------
__global__ __launch_bounds__(256)
void cast_bf16_k(const float4* __restrict__ in, uint4* __restrict__ out, long n8) {
  long i = (long)blockIdx.x * 256 + threadIdx.x;
  if (i >= n8) return;
  float4 a = in[2 * i], b = in[2 * i + 1];
  uint4 o;
  o.x = f2bf2(a.x, a.y); o.y = f2bf2(a.z, a.w);
  o.z = f2bf2(b.x, b.y); o.w = f2bf2(b.z, b.w);
  out[i] = o;
}

// ---------------- C = A(MxK) @ B(NxK)^T — 256^2 8-phase template ----------------
// LDS layout per tile (256x64 bf16 = 32 KiB): subtiled [rowblk16][colblk32][16][32],
// st_16x32 swizzle: inner byte ^= ((inner>>9)&1)<<5  (col-bit5 ^= row-bit3).
// global_load_lds writes LDS linearly -> global source is inverse-swizzled per lane.

// one phase's MFMA cluster: one A-quad x all 4 B-cols x one K-half = 16 MFMA
__device__ __forceinline__ void mfma_16(floatx4 (&acc)[8][4], const bf16x8 (&a)[4],
                                        const bf16x8 (&b)[4], int ib) {
#pragma unroll
  for (int i = 0; i < 4; ++i)
#pragma unroll
    for (int n = 0; n < 4; ++n)
      acc[ib + i][n] = __builtin_amdgcn_mfma_f32_16x16x32_bf16(
          a[i], b[n], acc[ib + i][n], 0, 0, 0);
}

template<int OUT_BF16>
__global__ __launch_bounds__(512, 2)
void gemm256_k(const u16* __restrict__ A, const u16* __restrict__ B,
               void* __restrict__ Cv, int N_, int K, int nbx)
{
  // buf b: A-tile at b*65536, B-tile at b*65536+32768
  __shared__ __align__(16) char smem[131072];

  // bijective XCD swizzle (grid % 8 == 0 by construction)
  const int nwg = (int)gridDim.x;
  const int id  = (int)blockIdx.x;
  const int swz = (id & 7) * (nwg >> 3) + (id >> 3);
  const int bx = swz % nbx, by = swz / nbx;
  const long tileM = (long)by << 8, tileN = (long)bx << 8;

  const int t = (int)threadIdx.x;
  const int wave = t >> 6, lane = t & 63;
  const int wm = wave >> 2, wn = wave & 3;      // 2 x 4 wave grid
  const int lrow = lane & 15, lkq = lane >> 4;

  // ---- staging: per-thread inverse-swizzled global source (16 B / lane / issue)
  const int o0   = t << 4;
  const int r0   = (o0 >> 6) & 15;
  const int c0   = (o0 & 63) ^ ((r0 & 8) << 2);          // inverse st_16x32 (involution)
  const int row0 = ((o0 >> 11) << 4) | r0;               // 0..63 (issue adds 64 rows)
  const int col0 = (((o0 >> 10) & 1) << 5) + (c0 >> 1);  // u16 col within K-step

  const u16* pA = A + (tileM + row0) * (long)K + col0;
  const u16* pB = B + (tileN + row0) * (long)K + col0;
  const long rs64 = (long)K << 6;   // 64 rows worth of u16 elements
  const int  nkt  = K >> 6;         // number of 64-wide K-tiles

  // ---- fragment ds_read bases (byte offsets, swizzle folded per-lane)
  const int innerF = (lrow << 6) | ((lkq << 4) ^ ((lrow & 8) << 2));
  const int aB = (wm << 14) + innerF;            // + rowblk*2048 + kk*1024
  const int bB = 32768 + (wn << 13) + innerF;    // + n*2048 + kk*1024

  floatx4 acc[8][4] = {};
  bf16x8 af[2][4], bv[2][4];

  // half-tile slots: 0=Bh0 1=Bh1 2=Ah0 3=Ah1 (2 global_load_lds each)
  auto stage = [&](int s, int j) {
    const int base = ((j & 1) << 16) + ((s < 2) ? 32768 : 0) + ((s & 1) << 14) + (wave << 10);
    const u16* src = (s < 2) ? pB : pA;
    const long gofs = (long)(s & 1) * 2 * rs64 + ((long)j << 6);
    __builtin_amdgcn_global_load_lds((GAS void*)(src + gofs),        (LAS void*)(smem + base),        16, 0, 0);
    __builtin_amdgcn_global_load_lds((GAS void*)(src + gofs + rs64), (LAS void*)(smem + base + 8192), 16, 0, 0);
  };

  // ---- prologue: B(0), A(0), B(1).  A(T) stages at tile T-1 ph0; B(T) at T-2 ph2.
  stage(0, 0); stage(1, 0); stage(2, 0); stage(3, 0);
  if (nkt > 1) { stage(0, 1); stage(1, 1); }
  if (nkt > 1) { asm volatile("s_waitcnt vmcnt(4)" ::: "memory"); }
  else         { asm volatile("s_waitcnt vmcnt(0)" ::: "memory"); }
  __builtin_amdgcn_s_barrier();
  __builtin_amdgcn_sched_barrier(0);

  for (int j = 0; j < nkt; ++j) {
    const int bufo = (j & 1) << 16;

    // ---------- phase 0: read bv[kk0] + af[kk0][quad0] (8 reads); stage A(j+1)
    {
#pragma unroll
      for (int n = 0; n < 4; ++n)
        bv[0][n] = *(const bf16x8*)(smem + bufo + bB + (n << 11));
#pragma unroll
      for (int i = 0; i < 4; ++i)
        af[0][i] = *(const bf16x8*)(smem + bufo + aB + (i << 11));
      if (j + 1 < nkt) { stage(2, j + 1); stage(3, j + 1); }
      __builtin_amdgcn_s_barrier();
      asm volatile("s_waitcnt lgkmcnt(0)" ::: "memory");
      __builtin_amdgcn_sched_barrier(0);
      __builtin_amdgcn_s_setprio(1);
      mfma_16(acc, af[0], bv[0], 0);
      __builtin_amdgcn_s_setprio(0);
      __builtin_amdgcn_s_barrier();
      __builtin_amdgcn_sched_barrier(0);
    }
    // ---------- phase 1: read bv[kk1] + af[kk1][quad0] (8 reads)
    {
#pragma unroll
      for (int n = 0; n < 4; ++n)
        bv[1][n] = *(const bf16x8*)(smem + bufo + bB + (n << 11) + 1024);
#pragma unroll
      for (int i = 0; i < 4; ++i)
        af[1][i] = *(const bf16x8*)(smem + bufo + aB + (i << 11) + 1024);
      __builtin_amdgcn_s_barrier();
      asm volatile("s_waitcnt lgkmcnt(0)" ::: "memory");
      __builtin_amdgcn_sched_barrier(0);
      __builtin_amdgcn_s_setprio(1);
      mfma_16(acc, af[1], bv[1], 0);
      __builtin_amdgcn_s_setprio(0);
      __builtin_amdgcn_s_barrier();
      __builtin_amdgcn_sched_barrier(0);
    }
    // ---------- phase 2: read af[kk0][quad1] (4 reads); stage B(j+2)
    {
#pragma unroll
      for (int i = 0; i < 4; ++i)
        af[0][i] = *(const bf16x8*)(smem + bufo + aB + ((4 + i) << 11));
      if (j + 2 < nkt) { stage(0, j + 2); stage(1, j + 2); }
      __builtin_amdgcn_s_barrier();
      asm volatile("s_waitcnt lgkmcnt(0)" ::: "memory");
      __builtin_amdgcn_sched_barrier(0);
      __builtin_amdgcn_s_setprio(1);
      mfma_16(acc, af[0], bv[0], 4);
      __builtin_amdgcn_s_setprio(0);
      __builtin_amdgcn_s_barrier();
      __builtin_amdgcn_sched_barrier(0);
    }
    // ---------- phase 3: read af[kk1][quad1] (4 reads); counted vmcnt
    {
#pragma unroll
      for (int i = 0; i < 4; ++i)
        af[1][i] = *(const bf16x8*)(smem + bufo + aB + ((4 + i) << 11) + 1024);
      __builtin_amdgcn_s_barrier();
      asm volatile("s_waitcnt lgkmcnt(0)" ::: "memory");
      __builtin_amdgcn_sched_barrier(0);
      __builtin_amdgcn_s_setprio(1);
      mfma_16(acc, af[1], bv[1], 4);
      __builtin_amdgcn_s_setprio(0);
      // B(j+2) (4 loads) may stay in flight; A(j+1)+B(j+1) must have landed
      if (j < nkt - 2)       { asm volatile("s_waitcnt vmcnt(4)" ::: "memory"); }
      else                   { asm volatile("s_waitcnt vmcnt(0)" ::: "memory"); }
      __builtin_amdgcn_s_barrier();
      __builtin_amdgcn_sched_barrier(0);
    }
  }

  // ---- epilogue: C/D layout col = lane&15, row = (lane>>4)*4 + reg
#pragma unroll
  for (int i = 0; i < 8; ++i) {
#pragma unroll
    for (int r = 0; r < 4; ++r) {
      const long row = tileM + wm * 128 + i * 16 + lkq * 4 + r;
#pragma unroll
      for (int n = 0; n < 4; ++n) {
        const long col = tileN + wn * 64 + n * 16 + lrow;
        const float v = acc[i][n][r];
        if (OUT_BF16) ((u16*)Cv)[row * (long)N_ + col] = f2bf(v);
        else          ((float*)Cv)[row * (long)N_ + col] = v;
      }
    }
  }
}

// ---------------- per-token 16-head x 16-head attention + permute ----------------
__global__ __launch_bounds__(256)
void attn_k(const u16* __restrict__ qkv, u16* __restrict__ y)
{
  __shared__ float sq[16 * 132];
  __shared__ float skT[128 * 17];
  __shared__ float sv[16 * 128];
  __shared__ float sS[16 * 17];
  __shared__ float sP[16 * 17];

  const int t = threadIdx.x;
  const int token = blockIdx.x;        // b*4096 + n
  const int n = token & 4095;
  const int b = token >> 12;
  const u16* base = qkv + (long)token * 6144;

  float f[8];
  { // q
    uint4 raw = *(const uint4*)(base + t * 8);
    unpack8(raw, f);
    float* dst = &sq[(t >> 4) * 132 + (t & 15) * 8];
    ((float4*)dst)[0] = make_float4(f[0], f[1], f[2], f[3]);
    ((float4*)dst)[1] = make_float4(f[4], f[5], f[6], f[7]);
  }
  { // k -> transposed
    uint4 raw = *(const uint4*)(base + 2048 + t * 8);
    unpack8(raw, f);
    const int j = t >> 4;
    const int d0 = (t & 15) * 8;
#pragma unroll
    for (int e = 0; e < 8; ++e) skT[(d0 + e) * 17 + j] = f[e];
  }
  { // v
    uint4 raw = *(const uint4*)(base + 4096 + t * 8);
    unpack8(raw, f);
    float* dst = &sv[t * 8];
    ((float4*)dst)[0] = make_float4(f[0], f[1], f[2], f[3]);
    ((float4*)dst)[1] = make_float4(f[4], f[5], f[6], f[7]);
  }
  __syncthreads();

  { // scores
    const int i = t >> 4, j = t & 15;
    const float* qi = &sq[i * 132];
    float s = 0.f;
#pragma unroll 16
    for (int d = 0; d < 128; ++d) s += qi[d] * skT[d * 17 + j];
    sS[i * 17 + j] = s * 0.08838834764831845f;
  }
  __syncthreads();

  { // softmax over j
    const int i = t >> 4, j = t & 15;
    float mx = -1e30f;
#pragma unroll
    for (int jj = 0; jj < 16; ++jj) mx = fmaxf(mx, sS[i * 17 + jj]);
    float sum = 0.f;
#pragma unroll
    for (int jj = 0; jj < 16; ++jj) sum += __expf(sS[i * 17 + jj] - mx);
    sP[i * 17 + j] = __expf(sS[i * 17 + j] - mx) / sum;
  }
  __syncthreads();

  { // out + permute
    const int i = t & 15, dblk = t >> 4;
    float o[8] = {};
#pragma unroll
    for (int jj = 0; jj < 16; ++jj) {
      const float p = sP[i * 17 + jj];
      const float* vv = &sv[jj * 128 + dblk * 8];
#pragma unroll
      for (int e = 0; e < 8; ++e) o[e] += p * vv[e];
    }
    const long row  = (long)b * 4096 + i * 256 + (n >> 4);
    const long colb = (long)(n & 15) * 128 + dblk * 8;
    uint4 pk;
    pk.x = f2bf2(o[0], o[1]); pk.y = f2bf2(o[2], o[3]);
    pk.z = f2bf2(o[4], o[5]); pk.w = f2bf2(o[6], o[7]);
    *(uint4*)&y[row * 2048 + colb] = pk;
  }
}

// ---------------- launch ----------------
extern "C" void kernel_launch(void* const* d_in, const int* in_sizes, int n_in,
                              void* d_out, int out_size, void* d_ws, size_t ws_size,
                              hipStream_t stream)
{
  const float* x      = (const float*)d_in[0];
  const float* w_qkv  = (const float*)d_in[1];
  const float* w_proj = (const float*)d_in[2];

  const long NX  = 67108864L;   // 8*4096*2048
  const long NWQ = 12582912L;   // 6144*2048
  const long NWP = 4194304L;    // 2048*2048
  const long NQKV = 32768L * 6144;
  const long NY   = 32768L * 2048;

  char* ws = (char*)d_ws;
  u16* xb   = (u16*)ws;  ws += NX * 2;
  u16* wqb  = (u16*)ws;  ws += NWQ * 2;
  u16* wpb  = (u16*)ws;  ws += NWP * 2;
  u16* qkvb = (u16*)ws;  ws += NQKV * 2;
  u16* yb   = (u16*)ws;  ws += NY * 2;
  if (ws_size < (size_t)704643072L) return;  // diagnostic: absmax stays ~454

  cast_bf16_k<<<dim3((u32)(NX  / 2048)), 256, 0, stream>>>((const float4*)x,      (uint4*)xb,  NX  / 8);
  cast_bf16_k<<<dim3((u32)(NWQ / 2048)), 256, 0, stream>>>((const float4*)w_qkv,  (uint4*)wqb, NWQ / 8);
  cast_bf16_k<<<dim3((u32)(NWP / 2048)), 256, 0, stream>>>((const float4*)w_proj, (uint4*)wpb, NWP / 8);

  // qkv = x @ w_qkv^T : M=32768, N=6144, K=2048 -> grid 24x128 = 3072 (%8==0)
  gemm256_k<1><<<dim3(24 * 128), 512, 0, stream>>>(xb, wqb, (void*)qkvb, 6144, 2048, 24);

  // head-attention + permute
  attn_k<<<dim3(32768), 256, 0, stream>>>(qkvb, yb);

  // out = y @ w_proj^T : M=32768, N=2048, K=2048 -> grid 8x128 = 1024 (%8==0)
  gemm256_k<0><<<dim3(8 * 128), 512, 0, stream>>>(yb, wpb, d_out, 2048, 2048, 8);
}